// Round 4
// baseline (1790.778 us; speedup 1.0000x reference)
//
#include <hip/hip_runtime.h>

#define T_TOK 4096
#define DDIM  1024
#define IDIM  2048
#define NE    8

typedef unsigned short u16;
typedef unsigned int   u32;

static __device__ __forceinline__ u16 f2bf(float f) {
  u32 u = __float_as_uint(f);
  u32 r = 0x7FFFu + ((u >> 16) & 1u);
  return (u16)((u + r) >> 16);
}
static __device__ __forceinline__ float bf2f(u16 v) {
  return __uint_as_float(((u32)v) << 16);
}

// ---- conf[t][e] = sigmoid(dot(x[t], Wc[e]) + bc[e]); one wave per token ----
__global__ __launch_bounds__(256) void conf_kernel(
    const float* __restrict__ x, const float* __restrict__ Wc,
    const float* __restrict__ bc, float* __restrict__ conf)
{
  int gid  = blockIdx.x * 256 + threadIdx.x;
  int t    = gid >> 6;
  int lane = threadIdx.x & 63;
  if (t >= T_TOK) return;
  const float* xr = x + (size_t)t * DDIM;
  float acc[NE];
#pragma unroll
  for (int e = 0; e < NE; e++) acc[e] = 0.f;
  for (int d = lane; d < DDIM; d += 64) {
    float xv = xr[d];
#pragma unroll
    for (int e = 0; e < NE; e++) acc[e] += xv * Wc[e * DDIM + d];
  }
#pragma unroll
  for (int off = 32; off > 0; off >>= 1) {
#pragma unroll
    for (int e = 0; e < NE; e++) acc[e] += __shfl_down(acc[e], off, 64);
  }
  if (lane == 0) {
#pragma unroll
    for (int e = 0; e < NE; e++)
      conf[t * NE + e] = 1.f / (1.f + expf(-(acc[e] + bc[e])));
  }
}

// ---- one thread per token: top-2 by conf (ties -> lower index), softmax ----
__global__ __launch_bounds__(256) void top2_kernel(
    const float* __restrict__ conf,
    int* __restrict__ counts, int* __restrict__ list, float* __restrict__ wlist)
{
  int t = blockIdx.x * 256 + threadIdx.x;
  if (t >= T_TOK) return;
  float c[NE];
#pragma unroll
  for (int e = 0; e < NE; e++) c[e] = conf[t * NE + e];
  int i0 = 0;
#pragma unroll
  for (int e = 1; e < NE; e++) if (c[e] > c[i0]) i0 = e;
  int i1 = (i0 == 0) ? 1 : 0;
#pragma unroll
  for (int e = 0; e < NE; e++) if (e != i0 && c[e] > c[i1]) i1 = e;
  // softmax over (v0, v1), v0 >= v1: w1 = 1/(1+e^(v0-v1)), w0 = 1-w1
  float w1 = 1.f / (1.f + expf(c[i0] - c[i1]));
  float w0 = 1.f - w1;
  int s0 = atomicAdd(&counts[i0], 1);
  list[i0 * T_TOK + s0]  = t;
  wlist[i0 * T_TOK + s0] = w0;
  int s1 = atomicAdd(&counts[i1], 1);
  list[i1 * T_TOK + s1]  = t;
  wlist[i1 * T_TOK + s1] = w1;
}

// ---- prefix sum over 8 experts ---------------------------------------------
__global__ void scan_kernel(const int* __restrict__ counts, int* __restrict__ base)
{
  if (threadIdx.x == 0 && blockIdx.x == 0) {
    int s = 0;
    for (int e = 0; e < NE; e++) { base[e] = s; s += counts[e]; }
    base[NE] = s;
  }
}

// ---- GEMM1: h = silu(x@Wg) * (x@Wu) * w over gathered rows -----------------
constexpr int TT = 64, TI = 128, BK = 16;

__global__ __launch_bounds__(256) void gemm1_kernel(
    const float* __restrict__ x, const float* __restrict__ Wg, const float* __restrict__ Wu,
    const int* __restrict__ counts, const int* __restrict__ base,
    const int* __restrict__ list, const float* __restrict__ wlist,
    u16* __restrict__ hbuf)
{
  const int e   = blockIdx.z;
  const int cnt = counts[e];
  const int p0  = blockIdx.y * TT;
  if (p0 >= cnt) return;
  const int i0  = blockIdx.x * TI;

  __shared__ __align__(16) float Xs[BK][TT];    // Xs[k][row]
  __shared__ __align__(16) float Wgs[BK][TI];   // Wgs[k][col]
  __shared__ __align__(16) float Wus[BK][TI];
  __shared__ int   tokS[TT];
  __shared__ float wS[TT];

  const int tid = threadIdx.x;
  if (tid < TT) {
    int p = p0 + tid;
    tokS[tid] = (p < cnt) ? list[e * T_TOK + p] : 0;
    wS[tid]   = (p < cnt) ? wlist[e * T_TOK + p] : 0.0f;
  }
  __syncthreads();

  float accg[8][4], accu[8][4];
#pragma unroll
  for (int i = 0; i < 8; i++)
#pragma unroll
    for (int j = 0; j < 4; j++) { accg[i][j] = 0.f; accu[i][j] = 0.f; }

  const int tr = tid >> 5;   // 0..7 : rows 8*tr .. 8*tr+7
  const int tc = tid & 31;   // 0..31: cols 4*tc .. 4*tc+3
  const float* Wge = Wg + (size_t)e * DDIM * IDIM + i0;
  const float* Wue = Wu + (size_t)e * DDIM * IDIM + i0;

  const int xrow = tid >> 2;         // 0..63
  const int xk4  = (tid & 3) * 4;    // 0,4,8,12
  const int wk   = tid >> 4;         // 0..15
  const int wc8  = (tid & 15) * 8;   // 0..120

  for (int k0 = 0; k0 < DDIM; k0 += BK) {
    {
      float4 v = *(const float4*)(x + (size_t)tokS[xrow] * DDIM + k0 + xk4);
      Xs[xk4 + 0][xrow] = v.x;
      Xs[xk4 + 1][xrow] = v.y;
      Xs[xk4 + 2][xrow] = v.z;
      Xs[xk4 + 3][xrow] = v.w;
    }
    {
      const float* gp = Wge + (size_t)(k0 + wk) * IDIM + wc8;
      const float* up = Wue + (size_t)(k0 + wk) * IDIM + wc8;
      float4 g0 = *(const float4*)(gp);
      float4 g1 = *(const float4*)(gp + 4);
      float4 u0 = *(const float4*)(up);
      float4 u1 = *(const float4*)(up + 4);
      Wgs[wk][wc8 + 0] = g0.x; Wgs[wk][wc8 + 1] = g0.y;
      Wgs[wk][wc8 + 2] = g0.z; Wgs[wk][wc8 + 3] = g0.w;
      Wgs[wk][wc8 + 4] = g1.x; Wgs[wk][wc8 + 5] = g1.y;
      Wgs[wk][wc8 + 6] = g1.z; Wgs[wk][wc8 + 7] = g1.w;
      Wus[wk][wc8 + 0] = u0.x; Wus[wk][wc8 + 1] = u0.y;
      Wus[wk][wc8 + 2] = u0.z; Wus[wk][wc8 + 3] = u0.w;
      Wus[wk][wc8 + 4] = u1.x; Wus[wk][wc8 + 5] = u1.y;
      Wus[wk][wc8 + 6] = u1.z; Wus[wk][wc8 + 7] = u1.w;
    }
    __syncthreads();
#pragma unroll
    for (int k = 0; k < BK; k++) {
      float xv[8], gv[4], uv[4];
#pragma unroll
      for (int rr = 0; rr < 8; rr++) xv[rr] = Xs[k][8 * tr + rr];
#pragma unroll
      for (int cc = 0; cc < 4; cc++) { gv[cc] = Wgs[k][4 * tc + cc]; uv[cc] = Wus[k][4 * tc + cc]; }
#pragma unroll
      for (int rr = 0; rr < 8; rr++)
#pragma unroll
        for (int cc = 0; cc < 4; cc++) {
          accg[rr][cc] = fmaf(xv[rr], gv[cc], accg[rr][cc]);
          accu[rr][cc] = fmaf(xv[rr], uv[cc], accu[rr][cc]);
        }
    }
    __syncthreads();
  }

  const int rowbase = base[e] + p0;
#pragma unroll
  for (int rr = 0; rr < 8; rr++) {
    int p = 8 * tr + rr;
    if (p0 + p >= cnt) continue;
    float w = wS[p];
    u16* hp = hbuf + (size_t)(rowbase + p) * IDIM + i0 + 4 * tc;
    ushort4 hv;
    { float g = accg[rr][0], u = accu[rr][0]; hv.x = f2bf(g / (1.f + expf(-g)) * u * w); }
    { float g = accg[rr][1], u = accu[rr][1]; hv.y = f2bf(g / (1.f + expf(-g)) * u * w); }
    { float g = accg[rr][2], u = accu[rr][2]; hv.z = f2bf(g / (1.f + expf(-g)) * u * w); }
    { float g = accg[rr][3], u = accu[rr][3]; hv.w = f2bf(g / (1.f + expf(-g)) * u * w); }
    *(ushort4*)hp = hv;
  }
}

// ---- GEMM2: out[tok,:] += h_row @ Wd[e]  (fp32 output, atomic combine) -----
__global__ __launch_bounds__(256) void gemm2_kernel(
    const u16* __restrict__ hbuf, const float* __restrict__ Wd,
    const int* __restrict__ counts, const int* __restrict__ base,
    const int* __restrict__ list,
    float* __restrict__ out)
{
  const int e   = blockIdx.z;
  const int cnt = counts[e];
  const int p0  = blockIdx.y * TT;
  if (p0 >= cnt) return;
  const int d0  = blockIdx.x * TI;

  __shared__ __align__(16) float Hs[BK][TT];
  __shared__ __align__(16) float Wds[BK][TI];
  __shared__ int tokS[TT];

  const int tid = threadIdx.x;
  if (tid < TT) {
    int p = p0 + tid;
    tokS[tid] = (p < cnt) ? list[e * T_TOK + p] : 0;
  }
  __syncthreads();

  float acc[8][4];
#pragma unroll
  for (int i = 0; i < 8; i++)
#pragma unroll
    for (int j = 0; j < 4; j++) acc[i][j] = 0.f;

  const int tr = tid >> 5, tc = tid & 31;
  const float* Wde = Wd + (size_t)e * IDIM * DDIM + d0;
  const int rowbase = base[e] + p0;

  const int hrow = tid >> 2;
  const int hk4  = (tid & 3) * 4;
  const int wk   = tid >> 4;
  const int wc8  = (tid & 15) * 8;

  for (int k0 = 0; k0 < IDIM; k0 += BK) {
    if (p0 + hrow < cnt) {
      const u16* hp = hbuf + (size_t)(rowbase + hrow) * IDIM + k0 + hk4;
      ushort4 v = *(const ushort4*)hp;
      Hs[hk4 + 0][hrow] = bf2f(v.x);
      Hs[hk4 + 1][hrow] = bf2f(v.y);
      Hs[hk4 + 2][hrow] = bf2f(v.z);
      Hs[hk4 + 3][hrow] = bf2f(v.w);
    } else {
      Hs[hk4 + 0][hrow] = 0.f; Hs[hk4 + 1][hrow] = 0.f;
      Hs[hk4 + 2][hrow] = 0.f; Hs[hk4 + 3][hrow] = 0.f;
    }
    {
      const float* dp = Wde + (size_t)(k0 + wk) * DDIM + wc8;
      float4 a = *(const float4*)(dp);
      float4 b = *(const float4*)(dp + 4);
      Wds[wk][wc8 + 0] = a.x; Wds[wk][wc8 + 1] = a.y;
      Wds[wk][wc8 + 2] = a.z; Wds[wk][wc8 + 3] = a.w;
      Wds[wk][wc8 + 4] = b.x; Wds[wk][wc8 + 5] = b.y;
      Wds[wk][wc8 + 6] = b.z; Wds[wk][wc8 + 7] = b.w;
    }
    __syncthreads();
#pragma unroll
    for (int k = 0; k < BK; k++) {
      float xv[8], dv[4];
#pragma unroll
      for (int rr = 0; rr < 8; rr++) xv[rr] = Hs[k][8 * tr + rr];
#pragma unroll
      for (int cc = 0; cc < 4; cc++) dv[cc] = Wds[k][4 * tc + cc];
#pragma unroll
      for (int rr = 0; rr < 8; rr++)
#pragma unroll
        for (int cc = 0; cc < 4; cc++)
          acc[rr][cc] = fmaf(xv[rr], dv[cc], acc[rr][cc]);
    }
    __syncthreads();
  }

#pragma unroll
  for (int rr = 0; rr < 8; rr++) {
    int p = 8 * tr + rr;
    if (p0 + p >= cnt) continue;
    int tok = tokS[p];
    float* op = out + (size_t)tok * DDIM + d0 + 4 * tc;
    atomicAdd(op + 0, acc[rr][0]);
    atomicAdd(op + 1, acc[rr][1]);
    atomicAdd(op + 2, acc[rr][2]);
    atomicAdd(op + 3, acc[rr][3]);
  }
}

// ---- launch -----------------------------------------------------------------
extern "C" void kernel_launch(void* const* d_in, const int* in_sizes, int n_in,
                              void* d_out, int out_size, void* d_ws, size_t ws_size,
                              hipStream_t stream)
{
  const float* x  = (const float*)d_in[0];
  const float* Wc = (const float*)d_in[1];
  const float* bc = (const float*)d_in[2];
  const float* Wg = (const float*)d_in[3];
  const float* Wu = (const float*)d_in[4];
  const float* Wd = (const float*)d_in[5];
  float* out = (float*)d_out;   // reference output dtype is float32

  char* ws = (char*)d_ws;
  int*   counts = (int*)(ws + 0);              // 32 B used
  int*   base   = (int*)(ws + 256);            // 36 B used
  float* conf   = (float*)(ws + 1024);         // 4096*8*4   = 128 KiB -> ends 132096
  int*   list   = (int*)(ws + 132096);         // 8*4096*4   = 128 KiB -> ends 263168
  float* wlist  = (float*)(ws + 263168);       // 128 KiB               -> ends 394240
  u16*   hbuf   = (u16*)(ws + 394240);         // 8192*2048*2 = 32 MiB  -> ends ~33.9 MiB

  hipMemsetAsync(counts, 0, 64, stream);
  hipMemsetAsync(out, 0, (size_t)out_size * sizeof(float), stream);  // fp32 accum target

  conf_kernel<<<T_TOK / 4, 256, 0, stream>>>(x, Wc, bc, conf);
  top2_kernel<<<T_TOK / 256, 256, 0, stream>>>(conf, counts, list, wlist);
  scan_kernel<<<1, 64, 0, stream>>>(counts, base);

  dim3 g1(IDIM / TI, T_TOK / TT, NE);
  gemm1_kernel<<<g1, 256, 0, stream>>>(x, Wg, Wu, counts, base, list, wlist, hbuf);

  dim3 g2(DDIM / TI, T_TOK / TT, NE);
  gemm2_kernel<<<g2, 256, 0, stream>>>(hbuf, Wd, counts, base, list, out);
}